// Round 3
// baseline (2641.995 us; speedup 1.0000x reference)
//
#include <hip/hip_runtime.h>

#define NN 50000
#define NE 800000

// ws element offsets (4-byte units), 64-aligned; O_EINFO 8B-aligned
#define O_DEGIN   0
#define O_DEGOUT  50048
#define O_ROWPTR  100096
#define O_CURSOR  150208
#define O_EINFO   200256
#define O_FEATN   1800256
#define O_ZF      3400256
#define O_ZNRD    3600320
#define O_VV      3800384
#define O_EZ      3800832
#define O_NFT     4600832
#define O_WDENT   6200832
#define O_YACC    6450880
#define O_H1      19250880
// end ~20.9M elems

// ---------------- setup kernels ----------------

__global__ __launch_bounds__(256) void k_deg(const int* __restrict__ src,
                                             const int* __restrict__ dst,
                                             int* degin, int* degout) {
    int e = blockIdx.x * 256 + threadIdx.x;
    if (e < NE) {
        atomicAdd(&degin[dst[e]], 1);
        atomicAdd(&degout[src[e]], 1);
    }
}

// single block, shuffle-based scan
__global__ __launch_bounds__(1024) void k_scan(const int* __restrict__ degin,
                                               int* rowptr, int* cursor) {
    __shared__ int swsum[16];
    __shared__ int stot;
    int t = threadIdx.x;
    int lane = t & 63, w = t >> 6;
    int carry = 0;
    for (int ch = 0; ch < 4; ch++) {
        int base = ch * 16384 + t * 16;
        int v[16];
        int s = 0;
#pragma unroll
        for (int j = 0; j < 16; j++) {
            v[j] = (base + j < NN) ? degin[base + j] : 0;
            s += v[j];
        }
        int incl = s;
#pragma unroll
        for (int off = 1; off < 64; off <<= 1) {
            int x = __shfl_up(incl, off, 64);
            if (lane >= off) incl += x;
        }
        if (lane == 63) swsum[w] = incl;
        __syncthreads();
        if (w == 0) {
            int y = (lane < 16) ? swsum[lane] : 0;
            int yi = y;
#pragma unroll
            for (int off = 1; off < 16; off <<= 1) {
                int x = __shfl_up(yi, off, 64);
                if (lane >= off) yi += x;
            }
            if (lane < 16) swsum[lane] = yi - y;
            if (lane == 15) stot = yi;
        }
        __syncthreads();
        int excl = carry + swsum[w] + (incl - s);
#pragma unroll
        for (int j = 0; j < 16; j++) {
            if (base + j < NN) { rowptr[base + j] = excl; cursor[base + j] = excl; }
            excl += v[j];
        }
        carry += stot;
        __syncthreads();
    }
    if (t == 0) rowptr[NN] = carry;
}

__global__ __launch_bounds__(256) void k_scatter(const int* __restrict__ src,
                                                 const int* __restrict__ dst,
                                                 const int* __restrict__ eid,
                                                 int* cursor, int2* einfo) {
    int e = blockIdx.x * 256 + threadIdx.x;
    if (e >= NE) return;
    int slot = atomicAdd(&cursor[dst[e]], 1);
    einfo[slot] = make_int2(src[e] | (eid[e] << 20), e);
}

// ---------------- per-layer kernels ----------------

// vvec[0:128]=ve[r][k] (We_r@aw2), [128:256]=vf[r][k], [256:384]=vd[r][k]
__global__ __launch_bounds__(384) void k_prevec(const float* __restrict__ Wr,
                                                const float* __restrict__ attw,
                                                float* __restrict__ vvec) {
    int t = threadIdx.x;
    int r = (t >> 5) & 3, k = t & 31, part = t >> 7;
    int row = (part == 0) ? (32 + k) : (part == 1) ? k : (64 + k);
    const float* wrow = Wr + (size_t)r * 3072 + row * 32;
    float s = 0.f;
#pragma unroll
    for (int c = 0; c < 32; c++) s += wrow[c] * attw[32 + c];
    vvec[t] = s;
}

// Thread per node: featn row, nfT column, zF[r][n], znrd[r][n]
__global__ __launch_bounds__(128) void k_nodeproj(const float* __restrict__ feat,
                                                  const float* __restrict__ nfeat,
                                                  const float* __restrict__ attw,
                                                  const float* __restrict__ vvec,
                                                  const int* __restrict__ degout,
                                                  float* __restrict__ featn,
                                                  float* __restrict__ nfT,
                                                  float* __restrict__ zF,
                                                  float* __restrict__ znrd) {
    int n = blockIdx.x * 128 + threadIdx.x;
    if (n >= NN) return;
    int dg = degout[n];
    float sc0 = rsqrtf((float)(dg > 1 ? dg : 1));
    const float* fin = feat + (size_t)n * 32;
    const float* nin = nfeat + (size_t)n * 32;
    float fv[32], nv[32];
#pragma unroll
    for (int k = 0; k < 32; k += 4) {
        float4 f4 = *(const float4*)&fin[k];
        fv[k] = f4.x * sc0; fv[k + 1] = f4.y * sc0;
        fv[k + 2] = f4.z * sc0; fv[k + 3] = f4.w * sc0;
        float4 n4 = *(const float4*)&nin[k];
        nv[k] = n4.x; nv[k + 1] = n4.y; nv[k + 2] = n4.z; nv[k + 3] = n4.w;
    }
    float* fo = featn + (size_t)n * 32;
#pragma unroll
    for (int k = 0; k < 32; k += 4)
        *(float4*)&fo[k] = make_float4(fv[k], fv[k + 1], fv[k + 2], fv[k + 3]);
#pragma unroll
    for (int k = 0; k < 32; k++) nfT[(size_t)k * NN + n] = nv[k];
    float zn = 0.f;
#pragma unroll
    for (int k = 0; k < 32; k++) zn += nv[k] * attw[k];
#pragma unroll
    for (int r = 0; r < 4; r++) {
        float zf = 0.f, zd = 0.f;
        const float* vf = vvec + 128 + r * 32;
        const float* vd = vvec + 256 + r * 32;
#pragma unroll
        for (int k = 0; k < 32; k++) { zf += fv[k] * vf[k]; zd += nv[k] * vd[k]; }
        zF[r * NN + n] = zf;
        znrd[r * NN + n] = zn + zd;
    }
}

// Flat edge-parallel: ez[e] = exp(leaky(znrd[r][d] + zF[r][s] + efeat[e].ve_r))
__global__ __launch_bounds__(256) void k_ez(const int* __restrict__ src,
                                            const int* __restrict__ dst,
                                            const int* __restrict__ eid,
                                            const float* __restrict__ efeat,
                                            const float* __restrict__ zF,
                                            const float* __restrict__ znrd,
                                            const float* __restrict__ vvec,
                                            float* __restrict__ ez) {
    int e = blockIdx.x * 256 + threadIdx.x;   // 3125*256 = NE exact
    int s = src[e], d = dst[e], r = eid[e];
    const float* er = efeat + (size_t)e * 32;
    float d0 = 0.f, d1 = 0.f, d2 = 0.f, d3 = 0.f;
#pragma unroll
    for (int k = 0; k < 32; k += 4) {
        float4 f = *(const float4*)&er[k];
        d0 += f.x * vvec[k]       + f.y * vvec[k + 1]
            + f.z * vvec[k + 2]   + f.w * vvec[k + 3];
        d1 += f.x * vvec[32 + k]  + f.y * vvec[33 + k]
            + f.z * vvec[34 + k]  + f.w * vvec[35 + k];
        d2 += f.x * vvec[64 + k]  + f.y * vvec[65 + k]
            + f.z * vvec[66 + k]  + f.w * vvec[67 + k];
        d3 += f.x * vvec[96 + k]  + f.y * vvec[97 + k]
            + f.z * vvec[98 + k]  + f.w * vvec[99 + k];
    }
    float dot = (r == 0) ? d0 : (r == 1) ? d1 : (r == 2) ? d2 : d3;
    float z = znrd[r * NN + d] + zF[r * NN + s] + dot;
    z = z > 0.f ? z : 0.01f * z;      // leaky_relu
    ez[e] = __expf(z);                // softmax max-shift cancels
}

// Wave per node, lane=(p,c): round-0's proven gather loop (2 edges/iter,
// scalar loads, 2-deep pipeline).  Tail: after xor-32 reduce every lane
// holds all 8 sums, so write row-major yacc[n][k], k = p*128 + r*32 + c,
// as 4 direct coalesced 256B global stores.  No LDS, no barrier, VGPR
// stays at round-0's 24 (epilogue GEMV deliberately NOT fused here:
// rounds 1-2 showed VGPR 44 halves occupancy and BW on this kernel).
__global__ __launch_bounds__(512) void k_agg(const int* __restrict__ rowptr,
                                             const int2* __restrict__ einfo,
                                             const float* __restrict__ ez,
                                             const float* __restrict__ efeat,
                                             const float* __restrict__ featn,
                                             float* __restrict__ yacc,
                                             float* __restrict__ wdenT) {
    int tid = threadIdx.x;
    int lane = tid & 63;
    int wid = tid >> 6;
    int n0 = blockIdx.x * 8;
    int n = n0 + wid;
    int c = lane & 31;
    int p = lane >> 5;

    int rp0 = rowptr[n];
    int deg = rowptr[n + 1] - rp0;

    float yf0 = 0.f, yf1 = 0.f, yf2 = 0.f, yf3 = 0.f;
    float ye0 = 0.f, ye1 = 0.f, ye2 = 0.f, ye3 = 0.f;
    float w0 = 0.f, w1 = 0.f, w2 = 0.f, w3 = 0.f, den = 0.f;

    int2 meA = make_int2(0, 0), meB = make_int2(0, 0);
    float ezA = 0.f, efA = 0.f, fnA = 0.f;
    if (p < deg) {
        meA = einfo[rp0 + p];
        ezA = ez[meA.y];
        efA = efeat[(size_t)meA.y * 32 + c];
        fnA = featn[(size_t)(meA.x & 0xFFFFF) * 32 + c];
    }
    if (p + 2 < deg) meB = einfo[rp0 + p + 2];

    for (int t = p; t < deg; t += 2) {
        float ezB = 0.f, efB = 0.f, fnB = 0.f;
        int2 meC = make_int2(0, 0);
        if (t + 2 < deg) {
            ezB = ez[meB.y];
            efB = efeat[(size_t)meB.y * 32 + c];
            fnB = featn[(size_t)(meB.x & 0xFFFFF) * 32 + c];
        }
        if (t + 4 < deg) meC = einfo[rp0 + t + 4];
        int rb = meA.x >> 20;
        float e0 = (rb == 0) ? ezA : 0.f;
        float e1 = (rb == 1) ? ezA : 0.f;
        float e2 = (rb == 2) ? ezA : 0.f;
        float e3 = (rb == 3) ? ezA : 0.f;
        yf0 += e0 * fnA; yf1 += e1 * fnA; yf2 += e2 * fnA; yf3 += e3 * fnA;
        ye0 += e0 * efA; ye1 += e1 * efA; ye2 += e2 * efA; ye3 += e3 * efA;
        w0 += e0; w1 += e1; w2 += e2; w3 += e3;
        den += ezA;
        meA = meB; ezA = ezB; efA = efB; fnA = fnB; meB = meC;
    }

    yf0 += __shfl_xor(yf0, 32); yf1 += __shfl_xor(yf1, 32);
    yf2 += __shfl_xor(yf2, 32); yf3 += __shfl_xor(yf3, 32);
    ye0 += __shfl_xor(ye0, 32); ye1 += __shfl_xor(ye1, 32);
    ye2 += __shfl_xor(ye2, 32); ye3 += __shfl_xor(ye3, 32);
    w0 += __shfl_xor(w0, 32); w1 += __shfl_xor(w1, 32);
    w2 += __shfl_xor(w2, 32); w3 += __shfl_xor(w3, 32);
    den += __shfl_xor(den, 32);

    if (lane < 5) {
        float wv = (lane == 0) ? w0 : (lane == 1) ? w1 : (lane == 2) ? w2
                 : (lane == 3) ? w3 : den;
        wdenT[lane * NN + n] = wv;
    }

    float* yr = yacc + (size_t)n * 256 + p * 128 + c;
    yr[0]  = p ? ye0 : yf0;
    yr[32] = p ? ye1 : yf1;
    yr[64] = p ? ye2 : yf2;
    yr[96] = p ? ye3 : yf3;
}

// Fused epilogue (was postA+postB): 256-thread block stages 8 nodes'
// yacc rows (8KB) + nfeat rows (1KB) into LDS coalesced; each 32-lane
// group owns one node, lane = output channel i.  Full 384x32 GEMV from
// uniform LDS broadcasts + L1-resident weights, then loop_w + norm +
// AMRM in-wave (LDS h-stage, shfl-reduce for the level scores).
__global__ __launch_bounds__(256) void k_postAB(const int* __restrict__ rowptr,
                                                const float* __restrict__ yacc,
                                                const float* __restrict__ wdenT,
                                                const float* __restrict__ nfeat,
                                                const float* __restrict__ Wr,
                                                const float* __restrict__ lw,
                                                const float* __restrict__ hbias,
                                                const float* __restrict__ aW,
                                                const float* __restrict__ ab,
                                                const float* __restrict__ aa,
                                                float* __restrict__ out) {
    __shared__ alignas(16) float sy[8 * 256];
    __shared__ alignas(16) float snf[8 * 32];
    __shared__ float sh[8 * 32];
    int tid = threadIdx.x;
    int n0 = blockIdx.x * 8;

    {
        const float4* ys = (const float4*)(yacc + (size_t)n0 * 256);
        float4* yd = (float4*)sy;
        yd[tid] = ys[tid];
        yd[tid + 256] = ys[tid + 256];
        snf[tid] = nfeat[(size_t)n0 * 32 + tid];
    }
    __syncthreads();

    int lane = tid & 63;
    int wid = tid >> 6;
    int g = lane >> 5, i = lane & 31;
    int node = wid * 2 + g;            // 0..7 within block
    int n = n0 + node;
    int deg = rowptr[n + 1] - rowptr[n];
    const float* row = sy + node * 256;
    const float* nv = snf + node * 32;

    float h = 0.f;
    // uf (part 0) / ue (part 1) GEMV: h += row[k] * Wr[r][wrow(k)][i]
#pragma unroll
    for (int part = 0; part < 2; part++) {
#pragma unroll
        for (int r = 0; r < 4; r++) {
            const float* W = Wr + (size_t)r * 3072 + (part ? 1024 : 0) + i;
            const float* rw = row + part * 128 + r * 32;
#pragma unroll
            for (int c = 0; c < 32; c += 4) {
                float4 v = *(const float4*)&rw[c];
                h += v.x * W[(size_t)c * 32] + v.y * W[(size_t)(c + 1) * 32]
                   + v.z * W[(size_t)(c + 2) * 32] + v.w * W[(size_t)(c + 3) * 32];
            }
        }
    }
    // Wd: h += wr_r * sum_c nv[c] * Wd_r[c][i]
#pragma unroll
    for (int r = 0; r < 4; r++) {
        float wr = wdenT[(size_t)r * NN + n];
        const float* W = Wr + (size_t)r * 3072 + 2048 + i;
        float t = 0.f;
#pragma unroll
        for (int c = 0; c < 32; c += 4) {
            float4 v = *(const float4*)&nv[c];
            t += v.x * W[(size_t)c * 32] + v.y * W[(size_t)(c + 1) * 32]
               + v.z * W[(size_t)(c + 2) * 32] + v.w * W[(size_t)(c + 3) * 32];
        }
        h += wr * t;
    }
    float den = wdenT[(size_t)4 * NN + n];
    h *= (deg > 0) ? 1.f / den : 0.f;
    // + nv @ lw
    {
        const float* L = lw + i;
#pragma unroll
        for (int c = 0; c < 32; c += 4) {
            float4 v = *(const float4*)&nv[c];
            h += v.x * L[(size_t)c * 32] + v.y * L[(size_t)(c + 1) * 32]
               + v.z * L[(size_t)(c + 2) * 32] + v.w * L[(size_t)(c + 3) * 32];
        }
    }
    float hsc = rsqrtf((float)(deg > 1 ? deg : 1));
    h = h * hsc + hbias[i];
    sh[node * 32 + i] = h;   // wave-private region: no __syncthreads needed

    // AMRM: lv[l][i] = relu(sum_k h[k]*aW[l][k][i] + ab[l][i]);
    // s[l] = sum_i lv[l][i]*aa[i] (5-step shfl reduce within the 32-group)
    float lv[3], s[3];
    const float* hn = sh + node * 32;
#pragma unroll
    for (int l = 0; l < 3; l++) {
        float a = ab[l * 32 + i];
        const float* A = aW + (size_t)l * 1024 + i;
#pragma unroll
        for (int c = 0; c < 32; c += 4) {
            float4 v = *(const float4*)&hn[c];
            a += v.x * A[(size_t)c * 32] + v.y * A[(size_t)(c + 1) * 32]
               + v.z * A[(size_t)(c + 2) * 32] + v.w * A[(size_t)(c + 3) * 32];
        }
        lv[l] = a > 0.f ? a : 0.f;
        float t = lv[l] * aa[i];
        t += __shfl_xor(t, 16); t += __shfl_xor(t, 8);
        t += __shfl_xor(t, 4);  t += __shfl_xor(t, 2);
        t += __shfl_xor(t, 1);
        s[l] = t;
    }
    float mx = fmaxf(s[0], fmaxf(s[1], s[2]));
    float e0 = __expf(s[0] - mx), e1 = __expf(s[1] - mx), e2 = __expf(s[2] - mx);
    float inv = 1.f / (e0 + e1 + e2);
    float o = (e0 * lv[0] + e1 * lv[1] + e2 * lv[2]) * inv;
    out[(size_t)n * 32 + i] = fmaxf(o, 0.f);
}

// ---------------- host ----------------

static void launch_layer(const float* feat, const float* nf, const float* efeat,
                         const int* src, const int* dst, const int* eid,
                         const float* Wr, const float* attw, const float* lw,
                         const float* hb, const float* aW, const float* ab,
                         const float* aa, float* wsf, int* wsi, float* out,
                         hipStream_t stream) {
    k_prevec<<<1, 384, 0, stream>>>(Wr, attw, wsf + O_VV);
    k_nodeproj<<<391, 128, 0, stream>>>(feat, nf, attw, wsf + O_VV, wsi + O_DEGOUT,
                                        wsf + O_FEATN, wsf + O_NFT,
                                        wsf + O_ZF, wsf + O_ZNRD);
    k_ez<<<3125, 256, 0, stream>>>(src, dst, eid, efeat, wsf + O_ZF, wsf + O_ZNRD,
                                   wsf + O_VV, wsf + O_EZ);
    k_agg<<<6250, 512, 0, stream>>>(wsi + O_ROWPTR, (const int2*)(wsi + O_EINFO),
                                    wsf + O_EZ, efeat, wsf + O_FEATN,
                                    wsf + O_YACC, wsf + O_WDENT);
    k_postAB<<<6250, 256, 0, stream>>>(wsi + O_ROWPTR, wsf + O_YACC, wsf + O_WDENT,
                                       nf, Wr, lw, hb, aW, ab, aa, out);
}

extern "C" void kernel_launch(void* const* d_in, const int* in_sizes, int n_in,
                              void* d_out, int out_size, void* d_ws, size_t ws_size,
                              hipStream_t stream) {
    const float* x     = (const float*)d_in[0];
    const float* nfeat = (const float*)d_in[1];
    const float* efeat = (const float*)d_in[2];
    const int*   src   = (const int*)d_in[3];
    const int*   dst   = (const int*)d_in[4];
    const int*   eid   = (const int*)d_in[5];
    const float* Wr1   = (const float*)d_in[6];
    const float* attw1 = (const float*)d_in[7];
    const float* lw1   = (const float*)d_in[8];
    const float* hb1   = (const float*)d_in[9];
    const float* aW1   = (const float*)d_in[10];
    const float* ab1   = (const float*)d_in[11];
    const float* aa1   = (const float*)d_in[12];
    const float* Wr2   = (const float*)d_in[13];
    const float* attw2 = (const float*)d_in[14];
    const float* lw2   = (const float*)d_in[15];
    const float* hb2   = (const float*)d_in[16];
    const float* aW2   = (const float*)d_in[17];
    const float* ab2   = (const float*)d_in[18];
    const float* aa2   = (const float*)d_in[19];

    float* wsf = (float*)d_ws;
    int*   wsi = (int*)d_ws;
    float* out = (float*)d_out;

    // zero degree counters (degin + degout)
    hipMemsetAsync(d_ws, 0, (size_t)O_ROWPTR * 4, stream);

    k_deg<<<NE / 256, 256, 0, stream>>>(src, dst, wsi + O_DEGIN, wsi + O_DEGOUT);
    k_scan<<<1, 1024, 0, stream>>>(wsi + O_DEGIN, wsi + O_ROWPTR, wsi + O_CURSOR);
    k_scatter<<<NE / 256, 256, 0, stream>>>(src, dst, eid, wsi + O_CURSOR,
                                            (int2*)(wsi + O_EINFO));

    // layer 1: feat = x -> h1 (ws)
    launch_layer(x, nfeat, efeat, src, dst, eid, Wr1, attw1, lw1, hb1, aW1, ab1, aa1,
                 wsf, wsi, wsf + O_H1, stream);
    // layer 2: feat = h1 -> d_out
    launch_layer(wsf + O_H1, nfeat, efeat, src, dst, eid, Wr2, attw2, lw2, hb2,
                 aW2, ab2, aa2, wsf, wsi, out, stream);
}

// Round 4
// 816.156 us; speedup vs baseline: 3.2371x; 3.2371x over previous
//
#include <hip/hip_runtime.h>

#define NN 50000
#define NE 800000

// ws element offsets (4-byte units), 64-aligned; O_EINFO 8B-aligned
#define O_DEGIN   0
#define O_DEGOUT  50048
#define O_ROWPTR  100096
#define O_CURSOR  150208
#define O_EINFO   200256
#define O_FEATN   1800256
#define O_ZF      3400256
#define O_ZNRD    3600320
#define O_VV      3800384
#define O_EZ      3800832
#define O_NFT     4600832
#define O_WDENT   6200832
#define O_YACCT   6450880
#define O_H1      19250880
// end ~20.9M elems

// ---------------- setup kernels ----------------

__global__ __launch_bounds__(256) void k_deg(const int* __restrict__ src,
                                             const int* __restrict__ dst,
                                             int* degin, int* degout) {
    int e = blockIdx.x * 256 + threadIdx.x;
    if (e < NE) {
        atomicAdd(&degin[dst[e]], 1);
        atomicAdd(&degout[src[e]], 1);
    }
}

// single block, shuffle-based scan
__global__ __launch_bounds__(1024) void k_scan(const int* __restrict__ degin,
                                               int* rowptr, int* cursor) {
    __shared__ int swsum[16];
    __shared__ int stot;
    int t = threadIdx.x;
    int lane = t & 63, w = t >> 6;
    int carry = 0;
    for (int ch = 0; ch < 4; ch++) {
        int base = ch * 16384 + t * 16;
        int v[16];
        int s = 0;
#pragma unroll
        for (int j = 0; j < 16; j++) {
            v[j] = (base + j < NN) ? degin[base + j] : 0;
            s += v[j];
        }
        int incl = s;
#pragma unroll
        for (int off = 1; off < 64; off <<= 1) {
            int x = __shfl_up(incl, off, 64);
            if (lane >= off) incl += x;
        }
        if (lane == 63) swsum[w] = incl;
        __syncthreads();
        if (w == 0) {
            int y = (lane < 16) ? swsum[lane] : 0;
            int yi = y;
#pragma unroll
            for (int off = 1; off < 16; off <<= 1) {
                int x = __shfl_up(yi, off, 64);
                if (lane >= off) yi += x;
            }
            if (lane < 16) swsum[lane] = yi - y;
            if (lane == 15) stot = yi;
        }
        __syncthreads();
        int excl = carry + swsum[w] + (incl - s);
#pragma unroll
        for (int j = 0; j < 16; j++) {
            if (base + j < NN) { rowptr[base + j] = excl; cursor[base + j] = excl; }
            excl += v[j];
        }
        carry += stot;
        __syncthreads();
    }
    if (t == 0) rowptr[NN] = carry;
}

__global__ __launch_bounds__(256) void k_scatter(const int* __restrict__ src,
                                                 const int* __restrict__ dst,
                                                 const int* __restrict__ eid,
                                                 int* cursor, int2* einfo) {
    int e = blockIdx.x * 256 + threadIdx.x;
    if (e >= NE) return;
    int slot = atomicAdd(&cursor[dst[e]], 1);
    einfo[slot] = make_int2(src[e] | (eid[e] << 20), e);
}

// ---------------- per-layer kernels ----------------

// vvec[0:128]=ve[r][k] (We_r@aw2), [128:256]=vf[r][k], [256:384]=vd[r][k]
__global__ __launch_bounds__(384) void k_prevec(const float* __restrict__ Wr,
                                                const float* __restrict__ attw,
                                                float* __restrict__ vvec) {
    int t = threadIdx.x;
    int r = (t >> 5) & 3, k = t & 31, part = t >> 7;
    int row = (part == 0) ? (32 + k) : (part == 1) ? k : (64 + k);
    const float* wrow = Wr + (size_t)r * 3072 + row * 32;
    float s = 0.f;
#pragma unroll
    for (int c = 0; c < 32; c++) s += wrow[c] * attw[32 + c];
    vvec[t] = s;
}

// Thread per node: featn row, nfT column, zF[r][n], znrd[r][n]
__global__ __launch_bounds__(128) void k_nodeproj(const float* __restrict__ feat,
                                                  const float* __restrict__ nfeat,
                                                  const float* __restrict__ attw,
                                                  const float* __restrict__ vvec,
                                                  const int* __restrict__ degout,
                                                  float* __restrict__ featn,
                                                  float* __restrict__ nfT,
                                                  float* __restrict__ zF,
                                                  float* __restrict__ znrd) {
    int n = blockIdx.x * 128 + threadIdx.x;
    if (n >= NN) return;
    int dg = degout[n];
    float sc0 = rsqrtf((float)(dg > 1 ? dg : 1));
    const float* fin = feat + (size_t)n * 32;
    const float* nin = nfeat + (size_t)n * 32;
    float fv[32], nv[32];
#pragma unroll
    for (int k = 0; k < 32; k += 4) {
        float4 f4 = *(const float4*)&fin[k];
        fv[k] = f4.x * sc0; fv[k + 1] = f4.y * sc0;
        fv[k + 2] = f4.z * sc0; fv[k + 3] = f4.w * sc0;
        float4 n4 = *(const float4*)&nin[k];
        nv[k] = n4.x; nv[k + 1] = n4.y; nv[k + 2] = n4.z; nv[k + 3] = n4.w;
    }
    float* fo = featn + (size_t)n * 32;
#pragma unroll
    for (int k = 0; k < 32; k += 4)
        *(float4*)&fo[k] = make_float4(fv[k], fv[k + 1], fv[k + 2], fv[k + 3]);
#pragma unroll
    for (int k = 0; k < 32; k++) nfT[(size_t)k * NN + n] = nv[k];
    float zn = 0.f;
#pragma unroll
    for (int k = 0; k < 32; k++) zn += nv[k] * attw[k];
#pragma unroll
    for (int r = 0; r < 4; r++) {
        float zf = 0.f, zd = 0.f;
        const float* vf = vvec + 128 + r * 32;
        const float* vd = vvec + 256 + r * 32;
#pragma unroll
        for (int k = 0; k < 32; k++) { zf += fv[k] * vf[k]; zd += nv[k] * vd[k]; }
        zF[r * NN + n] = zf;
        znrd[r * NN + n] = zn + zd;
    }
}

// Flat edge-parallel: ez[e] = exp(leaky(znrd[r][d] + zF[r][s] + efeat[e].ve_r))
__global__ __launch_bounds__(256) void k_ez(const int* __restrict__ src,
                                            const int* __restrict__ dst,
                                            const int* __restrict__ eid,
                                            const float* __restrict__ efeat,
                                            const float* __restrict__ zF,
                                            const float* __restrict__ znrd,
                                            const float* __restrict__ vvec,
                                            float* __restrict__ ez) {
    int e = blockIdx.x * 256 + threadIdx.x;   // 3125*256 = NE exact
    int s = src[e], d = dst[e], r = eid[e];
    const float* er = efeat + (size_t)e * 32;
    float d0 = 0.f, d1 = 0.f, d2 = 0.f, d3 = 0.f;
#pragma unroll
    for (int k = 0; k < 32; k += 4) {
        float4 f = *(const float4*)&er[k];
        d0 += f.x * vvec[k]       + f.y * vvec[k + 1]
            + f.z * vvec[k + 2]   + f.w * vvec[k + 3];
        d1 += f.x * vvec[32 + k]  + f.y * vvec[33 + k]
            + f.z * vvec[34 + k]  + f.w * vvec[35 + k];
        d2 += f.x * vvec[64 + k]  + f.y * vvec[65 + k]
            + f.z * vvec[66 + k]  + f.w * vvec[67 + k];
        d3 += f.x * vvec[96 + k]  + f.y * vvec[97 + k]
            + f.z * vvec[98 + k]  + f.w * vvec[99 + k];
    }
    float dot = (r == 0) ? d0 : (r == 1) ? d1 : (r == 2) ? d2 : d3;
    float z = znrd[r * NN + d] + zF[r * NN + s] + dot;
    z = z > 0.f ? z : 0.01f * z;      // leaky_relu
    ez[e] = __expf(z);                // softmax max-shift cancels
}

// Wave per node, lane=(p,c): ez-weighted raw-row accumulation, pipelined
// gathers; output transposed via LDS -> yaccT[k][n].  (round-0 proven:
// VGPR 24, occ ~75%, 2.44 TB/s — do NOT add epilogue work here.)
__global__ __launch_bounds__(512) void k_agg(const int* __restrict__ rowptr,
                                             const int2* __restrict__ einfo,
                                             const float* __restrict__ ez,
                                             const float* __restrict__ efeat,
                                             const float* __restrict__ featn,
                                             float* __restrict__ yaccT,
                                             float* __restrict__ wdenT) {
    __shared__ float sT[256 * 9];
    int tid = threadIdx.x;
    int lane = tid & 63;
    int wid = tid >> 6;
    int n0 = blockIdx.x * 8;
    int n = n0 + wid;
    int c = lane & 31;
    int p = lane >> 5;

    int rp0 = rowptr[n];
    int deg = rowptr[n + 1] - rp0;

    float yf0 = 0.f, yf1 = 0.f, yf2 = 0.f, yf3 = 0.f;
    float ye0 = 0.f, ye1 = 0.f, ye2 = 0.f, ye3 = 0.f;
    float w0 = 0.f, w1 = 0.f, w2 = 0.f, w3 = 0.f, den = 0.f;

    int2 meA = make_int2(0, 0), meB = make_int2(0, 0);
    float ezA = 0.f, efA = 0.f, fnA = 0.f;
    if (p < deg) {
        meA = einfo[rp0 + p];
        ezA = ez[meA.y];
        efA = efeat[(size_t)meA.y * 32 + c];
        fnA = featn[(size_t)(meA.x & 0xFFFFF) * 32 + c];
    }
    if (p + 2 < deg) meB = einfo[rp0 + p + 2];

    for (int t = p; t < deg; t += 2) {
        float ezB = 0.f, efB = 0.f, fnB = 0.f;
        int2 meC = make_int2(0, 0);
        if (t + 2 < deg) {
            ezB = ez[meB.y];
            efB = efeat[(size_t)meB.y * 32 + c];
            fnB = featn[(size_t)(meB.x & 0xFFFFF) * 32 + c];
        }
        if (t + 4 < deg) meC = einfo[rp0 + t + 4];
        int rb = meA.x >> 20;
        float e0 = (rb == 0) ? ezA : 0.f;
        float e1 = (rb == 1) ? ezA : 0.f;
        float e2 = (rb == 2) ? ezA : 0.f;
        float e3 = (rb == 3) ? ezA : 0.f;
        yf0 += e0 * fnA; yf1 += e1 * fnA; yf2 += e2 * fnA; yf3 += e3 * fnA;
        ye0 += e0 * efA; ye1 += e1 * efA; ye2 += e2 * efA; ye3 += e3 * efA;
        w0 += e0; w1 += e1; w2 += e2; w3 += e3;
        den += ezA;
        meA = meB; ezA = ezB; efA = efB; fnA = fnB; meB = meC;
    }

    yf0 += __shfl_xor(yf0, 32); yf1 += __shfl_xor(yf1, 32);
    yf2 += __shfl_xor(yf2, 32); yf3 += __shfl_xor(yf3, 32);
    ye0 += __shfl_xor(ye0, 32); ye1 += __shfl_xor(ye1, 32);
    ye2 += __shfl_xor(ye2, 32); ye3 += __shfl_xor(ye3, 32);
    w0 += __shfl_xor(w0, 32); w1 += __shfl_xor(w1, 32);
    w2 += __shfl_xor(w2, 32); w3 += __shfl_xor(w3, 32);
    den += __shfl_xor(den, 32);

    if (lane < 5) {
        float wv = (lane == 0) ? w0 : (lane == 1) ? w1 : (lane == 2) ? w2
                 : (lane == 3) ? w3 : den;
        wdenT[lane * NN + n] = wv;
    }

    {
        int kb = 128 * p + c;
        sT[(kb +  0) * 9 + wid] = p ? ye0 : yf0;
        sT[(kb + 32) * 9 + wid] = p ? ye1 : yf1;
        sT[(kb + 64) * 9 + wid] = p ? ye2 : yf2;
        sT[(kb + 96) * 9 + wid] = p ? ye3 : yf3;
    }
    __syncthreads();
    int k = tid >> 1, hf = tid & 1;
    float4 v = make_float4(sT[k * 9 + hf * 4 + 0], sT[k * 9 + hf * 4 + 1],
                           sT[k * 9 + hf * 4 + 2], sT[k * 9 + hf * 4 + 3]);
    *(float4*)&yaccT[(size_t)k * NN + n0 + hf * 4] = v;
}

// Merged epilogue (round-0 postA + postB bodies, pacc eliminated).
// Thread per node; r-loop kept rolled (#pragma unroll 1) so at most one
// relation's load stream is in flight — prevents the round-3 VGPR blowup.
// acc[i] = sum_r [ uf_r@Wf_r + ue_r@We_r + (wr_r*nv)@Wd_r ]; then
// h = acc*invden + nv@lw, *deg^-1/2 + bias, fused AMRM + relu -> out.
__global__ __launch_bounds__(256) void k_postAB(const int* __restrict__ rowptr,
                                                const float* __restrict__ yaccT,
                                                const float* __restrict__ wdenT,
                                                const float* __restrict__ nfT,
                                                const float* __restrict__ Wr,
                                                const float* __restrict__ lw,
                                                const float* __restrict__ hbias,
                                                const float* __restrict__ aW,
                                                const float* __restrict__ ab,
                                                const float* __restrict__ aa,
                                                float* __restrict__ out) {
    int n = blockIdx.x * 256 + threadIdx.x;
    if (n >= NN) return;
    int deg = rowptr[n + 1] - rowptr[n];
    float den = wdenT[(size_t)4 * NN + n];
    float invden = (deg > 0) ? 1.f / den : 0.f;

    float nv[32];
#pragma unroll
    for (int k = 0; k < 32; k++) nv[k] = nfT[(size_t)k * NN + n];

    float acc[32];
#pragma unroll
    for (int i = 0; i < 32; i++) acc[i] = 0.f;

#pragma unroll 1
    for (int r = 0; r < 4; r++) {
        float wr = wdenT[(size_t)r * NN + n];
        const float* W = Wr + (size_t)r * 3072;
        const float* ufc = yaccT + (size_t)(r * 32) * NN + n;
        const float* uec = yaccT + (size_t)(128 + r * 32) * NN + n;
        for (int k4 = 0; k4 < 32; k4 += 4) {
            float a0 = ufc[(size_t)(k4 + 0) * NN], a1 = ufc[(size_t)(k4 + 1) * NN];
            float a2 = ufc[(size_t)(k4 + 2) * NN], a3 = ufc[(size_t)(k4 + 3) * NN];
            float b0 = uec[(size_t)(k4 + 0) * NN], b1 = uec[(size_t)(k4 + 1) * NN];
            float b2 = uec[(size_t)(k4 + 2) * NN], b3 = uec[(size_t)(k4 + 3) * NN];
            float g0 = wr * nv[k4],     g1 = wr * nv[k4 + 1];
            float g2 = wr * nv[k4 + 2], g3 = wr * nv[k4 + 3];
            const float* Wk = W + k4 * 32;
#pragma unroll
            for (int i = 0; i < 32; i++)
                acc[i] += a0 * Wk[i]        + a1 * Wk[32 + i]
                        + a2 * Wk[64 + i]   + a3 * Wk[96 + i]
                        + b0 * Wk[1024 + i] + b1 * Wk[1056 + i]
                        + b2 * Wk[1088 + i] + b3 * Wk[1120 + i]
                        + g0 * Wk[2048 + i] + g1 * Wk[2080 + i]
                        + g2 * Wk[2112 + i] + g3 * Wk[2144 + i];
        }
    }

    float h[32];
#pragma unroll
    for (int i = 0; i < 32; i++) h[i] = acc[i] * invden;
    for (int k4 = 0; k4 < 32; k4 += 4) {
        const float* Lk = lw + k4 * 32;
#pragma unroll
        for (int i = 0; i < 32; i++)
            h[i] += nv[k4] * Lk[i] + nv[k4 + 1] * Lk[32 + i]
                  + nv[k4 + 2] * Lk[64 + i] + nv[k4 + 3] * Lk[96 + i];
    }
    float hsc = rsqrtf((float)(deg > 1 ? deg : 1));
#pragma unroll
    for (int i = 0; i < 32; i++) h[i] = h[i] * hsc + hbias[i];

    float s[3];
#pragma unroll 1
    for (int l = 0; l < 3; l++) {
        const float* A = aW + (size_t)l * 1024;
#pragma unroll
        for (int i = 0; i < 32; i++) acc[i] = ab[l * 32 + i];
        for (int k4 = 0; k4 < 32; k4 += 4) {
            const float* Ak = A + k4 * 32;
#pragma unroll
            for (int i = 0; i < 32; i++)
                acc[i] += h[k4] * Ak[i] + h[k4 + 1] * Ak[32 + i]
                        + h[k4 + 2] * Ak[64 + i] + h[k4 + 3] * Ak[96 + i];
        }
        float sl = 0.f;
#pragma unroll
        for (int i = 0; i < 32; i++) {
            float lv = acc[i] > 0.f ? acc[i] : 0.f;
            sl += lv * aa[i];
        }
        s[l] = sl;
    }
    float mx = fmaxf(s[0], fmaxf(s[1], s[2]));
    float e0 = __expf(s[0] - mx), e1 = __expf(s[1] - mx), e2 = __expf(s[2] - mx);
    float inv = 1.f / (e0 + e1 + e2);
    float scl[3] = {e0 * inv, e1 * inv, e2 * inv};

    float outv[32];
#pragma unroll
    for (int i = 0; i < 32; i++) outv[i] = 0.f;
#pragma unroll 1
    for (int l = 0; l < 3; l++) {
        const float* A = aW + (size_t)l * 1024;
#pragma unroll
        for (int i = 0; i < 32; i++) acc[i] = ab[l * 32 + i];
        for (int k4 = 0; k4 < 32; k4 += 4) {
            const float* Ak = A + k4 * 32;
#pragma unroll
            for (int i = 0; i < 32; i++)
                acc[i] += h[k4] * Ak[i] + h[k4 + 1] * Ak[32 + i]
                        + h[k4 + 2] * Ak[64 + i] + h[k4 + 3] * Ak[96 + i];
        }
#pragma unroll
        for (int i = 0; i < 32; i++) {
            float lv = acc[i] > 0.f ? acc[i] : 0.f;
            outv[i] += scl[l] * lv;
        }
    }
    float* op = out + (size_t)n * 32;
#pragma unroll
    for (int i = 0; i < 32; i += 4)
        *(float4*)&op[i] = make_float4(fmaxf(outv[i], 0.f), fmaxf(outv[i + 1], 0.f),
                                       fmaxf(outv[i + 2], 0.f), fmaxf(outv[i + 3], 0.f));
}

// ---------------- host ----------------

static void launch_layer(const float* feat, const float* nf, const float* efeat,
                         const int* src, const int* dst, const int* eid,
                         const float* Wr, const float* attw, const float* lw,
                         const float* hb, const float* aW, const float* ab,
                         const float* aa, float* wsf, int* wsi, float* out,
                         hipStream_t stream) {
    k_prevec<<<1, 384, 0, stream>>>(Wr, attw, wsf + O_VV);
    k_nodeproj<<<391, 128, 0, stream>>>(feat, nf, attw, wsf + O_VV, wsi + O_DEGOUT,
                                        wsf + O_FEATN, wsf + O_NFT,
                                        wsf + O_ZF, wsf + O_ZNRD);
    k_ez<<<3125, 256, 0, stream>>>(src, dst, eid, efeat, wsf + O_ZF, wsf + O_ZNRD,
                                   wsf + O_VV, wsf + O_EZ);
    k_agg<<<6250, 512, 0, stream>>>(wsi + O_ROWPTR, (const int2*)(wsi + O_EINFO),
                                    wsf + O_EZ, efeat, wsf + O_FEATN,
                                    wsf + O_YACCT, wsf + O_WDENT);
    k_postAB<<<196, 256, 0, stream>>>(wsi + O_ROWPTR, wsf + O_YACCT, wsf + O_WDENT,
                                      wsf + O_NFT, Wr, lw, hb, aW, ab, aa, out);
}

extern "C" void kernel_launch(void* const* d_in, const int* in_sizes, int n_in,
                              void* d_out, int out_size, void* d_ws, size_t ws_size,
                              hipStream_t stream) {
    const float* x     = (const float*)d_in[0];
    const float* nfeat = (const float*)d_in[1];
    const float* efeat = (const float*)d_in[2];
    const int*   src   = (const int*)d_in[3];
    const int*   dst   = (const int*)d_in[4];
    const int*   eid   = (const int*)d_in[5];
    const float* Wr1   = (const float*)d_in[6];
    const float* attw1 = (const float*)d_in[7];
    const float* lw1   = (const float*)d_in[8];
    const float* hb1   = (const float*)d_in[9];
    const float* aW1   = (const float*)d_in[10];
    const float* ab1   = (const float*)d_in[11];
    const float* aa1   = (const float*)d_in[12];
    const float* Wr2   = (const float*)d_in[13];
    const float* attw2 = (const float*)d_in[14];
    const float* lw2   = (const float*)d_in[15];
    const float* hb2   = (const float*)d_in[16];
    const float* aW2   = (const float*)d_in[17];
    const float* ab2   = (const float*)d_in[18];
    const float* aa2   = (const float*)d_in[19];

    float* wsf = (float*)d_ws;
    int*   wsi = (int*)d_ws;
    float* out = (float*)d_out;

    // zero degree counters (degin + degout)
    hipMemsetAsync(d_ws, 0, (size_t)O_ROWPTR * 4, stream);

    k_deg<<<NE / 256, 256, 0, stream>>>(src, dst, wsi + O_DEGIN, wsi + O_DEGOUT);
    k_scan<<<1, 1024, 0, stream>>>(wsi + O_DEGIN, wsi + O_ROWPTR, wsi + O_CURSOR);
    k_scatter<<<NE / 256, 256, 0, stream>>>(src, dst, eid, wsi + O_CURSOR,
                                            (int2*)(wsi + O_EINFO));

    // layer 1: feat = x -> h1 (ws)
    launch_layer(x, nfeat, efeat, src, dst, eid, Wr1, attw1, lw1, hb1, aW1, ab1, aa1,
                 wsf, wsi, wsf + O_H1, stream);
    // layer 2: feat = h1 -> d_out
    launch_layer(wsf + O_H1, nfeat, efeat, src, dst, eid, Wr2, attw2, lw2, hb2,
                 aW2, ab2, aa2, wsf, wsi, out, stream);
}

// Round 5
// 726.102 us; speedup vs baseline: 3.6386x; 1.1240x over previous
//
#include <hip/hip_runtime.h>

#define NN 50000
#define NE 800000

// ws element offsets (4-byte units), 64-aligned; O_EINFO 8B-aligned
#define O_DEGIN   0
#define O_DEGOUT  50048
#define O_ROWPTR  100096
#define O_CURSOR  150208
#define O_EINFO   200256
#define O_FEATN   1800256
#define O_ZF      3400256
#define O_ZNRD    3600320
#define O_VV      3800384
#define O_EZ      3800832
#define O_NFT     4600832
#define O_WDENT   6200832
#define O_YACC    6450880
#define O_H1      19250880
// end ~20.9M elems

// ---------------- setup kernels ----------------

__global__ __launch_bounds__(256) void k_deg(const int* __restrict__ src,
                                             const int* __restrict__ dst,
                                             int* degin, int* degout) {
    int e = blockIdx.x * 256 + threadIdx.x;
    if (e < NE) {
        atomicAdd(&degin[dst[e]], 1);
        atomicAdd(&degout[src[e]], 1);
    }
}

// single block, shuffle-based scan
__global__ __launch_bounds__(1024) void k_scan(const int* __restrict__ degin,
                                               int* rowptr, int* cursor) {
    __shared__ int swsum[16];
    __shared__ int stot;
    int t = threadIdx.x;
    int lane = t & 63, w = t >> 6;
    int carry = 0;
    for (int ch = 0; ch < 4; ch++) {
        int base = ch * 16384 + t * 16;
        int v[16];
        int s = 0;
#pragma unroll
        for (int j = 0; j < 16; j++) {
            v[j] = (base + j < NN) ? degin[base + j] : 0;
            s += v[j];
        }
        int incl = s;
#pragma unroll
        for (int off = 1; off < 64; off <<= 1) {
            int x = __shfl_up(incl, off, 64);
            if (lane >= off) incl += x;
        }
        if (lane == 63) swsum[w] = incl;
        __syncthreads();
        if (w == 0) {
            int y = (lane < 16) ? swsum[lane] : 0;
            int yi = y;
#pragma unroll
            for (int off = 1; off < 16; off <<= 1) {
                int x = __shfl_up(yi, off, 64);
                if (lane >= off) yi += x;
            }
            if (lane < 16) swsum[lane] = yi - y;
            if (lane == 15) stot = yi;
        }
        __syncthreads();
        int excl = carry + swsum[w] + (incl - s);
#pragma unroll
        for (int j = 0; j < 16; j++) {
            if (base + j < NN) { rowptr[base + j] = excl; cursor[base + j] = excl; }
            excl += v[j];
        }
        carry += stot;
        __syncthreads();
    }
    if (t == 0) rowptr[NN] = carry;
}

__global__ __launch_bounds__(256) void k_scatter(const int* __restrict__ src,
                                                 const int* __restrict__ dst,
                                                 const int* __restrict__ eid,
                                                 int* cursor, int2* einfo) {
    int e = blockIdx.x * 256 + threadIdx.x;
    if (e >= NE) return;
    int slot = atomicAdd(&cursor[dst[e]], 1);
    einfo[slot] = make_int2(src[e] | (eid[e] << 20), e);
}

// ---------------- per-layer kernels ----------------

// vvec[0:128]=ve[r][k] (We_r@aw2), [128:256]=vf[r][k], [256:384]=vd[r][k]
__global__ __launch_bounds__(384) void k_prevec(const float* __restrict__ Wr,
                                                const float* __restrict__ attw,
                                                float* __restrict__ vvec) {
    int t = threadIdx.x;
    int r = (t >> 5) & 3, k = t & 31, part = t >> 7;
    int row = (part == 0) ? (32 + k) : (part == 1) ? k : (64 + k);
    const float* wrow = Wr + (size_t)r * 3072 + row * 32;
    float s = 0.f;
#pragma unroll
    for (int c = 0; c < 32; c++) s += wrow[c] * attw[32 + c];
    vvec[t] = s;
}

// Thread per node: featn row, nfT column, zF[r][n], znrd[r][n]
__global__ __launch_bounds__(128) void k_nodeproj(const float* __restrict__ feat,
                                                  const float* __restrict__ nfeat,
                                                  const float* __restrict__ attw,
                                                  const float* __restrict__ vvec,
                                                  const int* __restrict__ degout,
                                                  float* __restrict__ featn,
                                                  float* __restrict__ nfT,
                                                  float* __restrict__ zF,
                                                  float* __restrict__ znrd) {
    int n = blockIdx.x * 128 + threadIdx.x;
    if (n >= NN) return;
    int dg = degout[n];
    float sc0 = rsqrtf((float)(dg > 1 ? dg : 1));
    const float* fin = feat + (size_t)n * 32;
    const float* nin = nfeat + (size_t)n * 32;
    float fv[32], nv[32];
#pragma unroll
    for (int k = 0; k < 32; k += 4) {
        float4 f4 = *(const float4*)&fin[k];
        fv[k] = f4.x * sc0; fv[k + 1] = f4.y * sc0;
        fv[k + 2] = f4.z * sc0; fv[k + 3] = f4.w * sc0;
        float4 n4 = *(const float4*)&nin[k];
        nv[k] = n4.x; nv[k + 1] = n4.y; nv[k + 2] = n4.z; nv[k + 3] = n4.w;
    }
    float* fo = featn + (size_t)n * 32;
#pragma unroll
    for (int k = 0; k < 32; k += 4)
        *(float4*)&fo[k] = make_float4(fv[k], fv[k + 1], fv[k + 2], fv[k + 3]);
#pragma unroll
    for (int k = 0; k < 32; k++) nfT[(size_t)k * NN + n] = nv[k];
    float zn = 0.f;
#pragma unroll
    for (int k = 0; k < 32; k++) zn += nv[k] * attw[k];
#pragma unroll
    for (int r = 0; r < 4; r++) {
        float zf = 0.f, zd = 0.f;
        const float* vf = vvec + 128 + r * 32;
        const float* vd = vvec + 256 + r * 32;
#pragma unroll
        for (int k = 0; k < 32; k++) { zf += fv[k] * vf[k]; zd += nv[k] * vd[k]; }
        zF[r * NN + n] = zf;
        znrd[r * NN + n] = zn + zd;
    }
}

// Flat edge-parallel: ez[e] = exp(leaky(znrd[r][d] + zF[r][s] + efeat[e].ve_r))
__global__ __launch_bounds__(256) void k_ez(const int* __restrict__ src,
                                            const int* __restrict__ dst,
                                            const int* __restrict__ eid,
                                            const float* __restrict__ efeat,
                                            const float* __restrict__ zF,
                                            const float* __restrict__ znrd,
                                            const float* __restrict__ vvec,
                                            float* __restrict__ ez) {
    int e = blockIdx.x * 256 + threadIdx.x;   // 3125*256 = NE exact
    int s = src[e], d = dst[e], r = eid[e];
    const float* er = efeat + (size_t)e * 32;
    float d0 = 0.f, d1 = 0.f, d2 = 0.f, d3 = 0.f;
#pragma unroll
    for (int k = 0; k < 32; k += 4) {
        float4 f = *(const float4*)&er[k];
        d0 += f.x * vvec[k]       + f.y * vvec[k + 1]
            + f.z * vvec[k + 2]   + f.w * vvec[k + 3];
        d1 += f.x * vvec[32 + k]  + f.y * vvec[33 + k]
            + f.z * vvec[34 + k]  + f.w * vvec[35 + k];
        d2 += f.x * vvec[64 + k]  + f.y * vvec[65 + k]
            + f.z * vvec[66 + k]  + f.w * vvec[67 + k];
        d3 += f.x * vvec[96 + k]  + f.y * vvec[97 + k]
            + f.z * vvec[98 + k]  + f.w * vvec[99 + k];
    }
    float dot = (r == 0) ? d0 : (r == 1) ? d1 : (r == 2) ? d2 : d3;
    float z = znrd[r * NN + d] + zF[r * NN + s] + dot;
    z = z > 0.f ? z : 0.01f * z;      // leaky_relu
    ez[e] = __expf(z);                // softmax max-shift cancels
}

// Wave per node, lane=(p,c): round-0's proven gather loop (2 edges/iter,
// scalar loads, 2-deep pipeline).  Tail: after xor-32 reduce every lane
// holds all 8 sums; write row-major yacc[n][k], k = p*128 + r*32 + c, as
// 4 direct coalesced 256B stores.  No LDS, no barrier, VGPR ~24.
// (Epilogue deliberately NOT fused: rounds 1-2 showed VGPR 44 halves
// occupancy and gather BW here.)
__global__ __launch_bounds__(512) void k_agg(const int* __restrict__ rowptr,
                                             const int2* __restrict__ einfo,
                                             const float* __restrict__ ez,
                                             const float* __restrict__ efeat,
                                             const float* __restrict__ featn,
                                             float* __restrict__ yacc,
                                             float* __restrict__ wdenT) {
    int tid = threadIdx.x;
    int lane = tid & 63;
    int wid = tid >> 6;
    int n0 = blockIdx.x * 8;
    int n = n0 + wid;
    int c = lane & 31;
    int p = lane >> 5;

    int rp0 = rowptr[n];
    int deg = rowptr[n + 1] - rp0;

    float yf0 = 0.f, yf1 = 0.f, yf2 = 0.f, yf3 = 0.f;
    float ye0 = 0.f, ye1 = 0.f, ye2 = 0.f, ye3 = 0.f;
    float w0 = 0.f, w1 = 0.f, w2 = 0.f, w3 = 0.f, den = 0.f;

    int2 meA = make_int2(0, 0), meB = make_int2(0, 0);
    float ezA = 0.f, efA = 0.f, fnA = 0.f;
    if (p < deg) {
        meA = einfo[rp0 + p];
        ezA = ez[meA.y];
        efA = efeat[(size_t)meA.y * 32 + c];
        fnA = featn[(size_t)(meA.x & 0xFFFFF) * 32 + c];
    }
    if (p + 2 < deg) meB = einfo[rp0 + p + 2];

    for (int t = p; t < deg; t += 2) {
        float ezB = 0.f, efB = 0.f, fnB = 0.f;
        int2 meC = make_int2(0, 0);
        if (t + 2 < deg) {
            ezB = ez[meB.y];
            efB = efeat[(size_t)meB.y * 32 + c];
            fnB = featn[(size_t)(meB.x & 0xFFFFF) * 32 + c];
        }
        if (t + 4 < deg) meC = einfo[rp0 + t + 4];
        int rb = meA.x >> 20;
        float e0 = (rb == 0) ? ezA : 0.f;
        float e1 = (rb == 1) ? ezA : 0.f;
        float e2 = (rb == 2) ? ezA : 0.f;
        float e3 = (rb == 3) ? ezA : 0.f;
        yf0 += e0 * fnA; yf1 += e1 * fnA; yf2 += e2 * fnA; yf3 += e3 * fnA;
        ye0 += e0 * efA; ye1 += e1 * efA; ye2 += e2 * efA; ye3 += e3 * efA;
        w0 += e0; w1 += e1; w2 += e2; w3 += e3;
        den += ezA;
        meA = meB; ezA = ezB; efA = efB; fnA = fnB; meB = meC;
    }

    yf0 += __shfl_xor(yf0, 32); yf1 += __shfl_xor(yf1, 32);
    yf2 += __shfl_xor(yf2, 32); yf3 += __shfl_xor(yf3, 32);
    ye0 += __shfl_xor(ye0, 32); ye1 += __shfl_xor(ye1, 32);
    ye2 += __shfl_xor(ye2, 32); ye3 += __shfl_xor(ye3, 32);
    w0 += __shfl_xor(w0, 32); w1 += __shfl_xor(w1, 32);
    w2 += __shfl_xor(w2, 32); w3 += __shfl_xor(w3, 32);
    den += __shfl_xor(den, 32);

    if (lane < 5) {
        float wv = (lane == 0) ? w0 : (lane == 1) ? w1 : (lane == 2) ? w2
                 : (lane == 3) ? w3 : den;
        wdenT[lane * NN + n] = wv;
    }

    float* yr = yacc + (size_t)n * 256 + p * 128 + c;
    yr[0]  = p ? ye0 : yf0;
    yr[32] = p ? ye1 : yf1;
    yr[64] = p ? ye2 : yf2;
    yr[96] = p ? ye3 : yf3;
}

// Fused epilogue with WIDTH (round-3 shape) and register discipline
// (round-4 lesson): 6250 blocks x 256 thr, 8 nodes/block staged into LDS
// coalesced; 32-lane group per node, lane = output channel i.  Main GEMV
// is a rolled 8-iteration pr-loop (<=32 weight loads in flight; round-3's
// full unroll hit VGPR 256 + 1.1GB scratch spill).  AMRM uses 3 named
// accumulators + rolled c-loop (no runtime-indexed arrays -> no scratch).
__global__ __launch_bounds__(256) void k_postAB(const int* __restrict__ rowptr,
                                                const float* __restrict__ yacc,
                                                const float* __restrict__ wdenT,
                                                const float* __restrict__ nfeat,
                                                const float* __restrict__ Wr,
                                                const float* __restrict__ lw,
                                                const float* __restrict__ hbias,
                                                const float* __restrict__ aW,
                                                const float* __restrict__ ab,
                                                const float* __restrict__ aa,
                                                float* __restrict__ out) {
    __shared__ alignas(16) float sy[8 * 256];
    __shared__ alignas(16) float snf[8 * 32];
    __shared__ float sh[8 * 32];
    int tid = threadIdx.x;
    int n0 = blockIdx.x * 8;

    {
        const float4* ys = (const float4*)(yacc + (size_t)n0 * 256);
        float4* yd = (float4*)sy;
        yd[tid] = ys[tid];
        yd[tid + 256] = ys[tid + 256];
        snf[tid] = nfeat[(size_t)n0 * 32 + tid];
    }
    __syncthreads();

    int lane = tid & 63;
    int wid = tid >> 6;
    int g = lane >> 5, i = lane & 31;
    int node = wid * 2 + g;            // 0..7 within block
    int n = n0 + node;
    int deg = rowptr[n + 1] - rowptr[n];
    const float* row = sy + node * 256;
    const float* nv = snf + node * 32;

    float h = 0.f;
    // uf/ue GEMV, rolled: pr = part*4 + r; row slice is row[pr*32 + c],
    // weight column Wr[r][part*32 + c][i].
#pragma unroll 1
    for (int pr = 0; pr < 8; pr++) {
        int part = pr >> 2, r = pr & 3;
        const float* W = Wr + (size_t)r * 3072 + part * 1024 + i;
        const float* rw = row + pr * 32;
        float t = 0.f;
#pragma unroll
        for (int c = 0; c < 32; c += 4) {
            float4 v = *(const float4*)&rw[c];
            t += v.x * W[(size_t)c * 32] + v.y * W[(size_t)(c + 1) * 32]
               + v.z * W[(size_t)(c + 2) * 32] + v.w * W[(size_t)(c + 3) * 32];
        }
        h += t;
    }
    // Wd: h += wr_r * sum_c nv[c] * Wd_r[c][i]
#pragma unroll 1
    for (int r = 0; r < 4; r++) {
        float wr = wdenT[(size_t)r * NN + n];
        const float* W = Wr + (size_t)r * 3072 + 2048 + i;
        float t = 0.f;
#pragma unroll
        for (int c = 0; c < 32; c += 4) {
            float4 v = *(const float4*)&nv[c];
            t += v.x * W[(size_t)c * 32] + v.y * W[(size_t)(c + 1) * 32]
               + v.z * W[(size_t)(c + 2) * 32] + v.w * W[(size_t)(c + 3) * 32];
        }
        h += wr * t;
    }
    float den = wdenT[(size_t)4 * NN + n];
    h *= (deg > 0) ? 1.f / den : 0.f;
    // + nv @ lw
    {
        const float* L = lw + i;
        float t = 0.f;
#pragma unroll
        for (int c = 0; c < 32; c += 4) {
            float4 v = *(const float4*)&nv[c];
            t += v.x * L[(size_t)c * 32] + v.y * L[(size_t)(c + 1) * 32]
               + v.z * L[(size_t)(c + 2) * 32] + v.w * L[(size_t)(c + 3) * 32];
        }
        h += t;
    }
    float hsc = rsqrtf((float)(deg > 1 ? deg : 1));
    h = h * hsc + hbias[i];
    sh[node * 32 + i] = h;   // wave-private region: no barrier needed

    // AMRM: 3 named level accumulators, rolled c-loop (12 loads/iter).
    const float* hn = sh + node * 32;
    float a0 = ab[i], a1 = ab[32 + i], a2 = ab[64 + i];
#pragma unroll 1
    for (int c = 0; c < 32; c += 4) {
        float4 v = *(const float4*)&hn[c];
        const float* A0 = aW + (size_t)c * 32 + i;
        const float* A1 = aW + 1024 + (size_t)c * 32 + i;
        const float* A2 = aW + 2048 + (size_t)c * 32 + i;
        a0 += v.x * A0[0] + v.y * A0[32] + v.z * A0[64] + v.w * A0[96];
        a1 += v.x * A1[0] + v.y * A1[32] + v.z * A1[64] + v.w * A1[96];
        a2 += v.x * A2[0] + v.y * A2[32] + v.z * A2[64] + v.w * A2[96];
    }
    float lv0 = a0 > 0.f ? a0 : 0.f;
    float lv1 = a1 > 0.f ? a1 : 0.f;
    float lv2 = a2 > 0.f ? a2 : 0.f;
    float aai = aa[i];
    float s0 = lv0 * aai, s1 = lv1 * aai, s2 = lv2 * aai;
#pragma unroll
    for (int off = 16; off >= 1; off >>= 1) {
        s0 += __shfl_xor(s0, off);
        s1 += __shfl_xor(s1, off);
        s2 += __shfl_xor(s2, off);
    }
    float mx = fmaxf(s0, fmaxf(s1, s2));
    float e0 = __expf(s0 - mx), e1 = __expf(s1 - mx), e2 = __expf(s2 - mx);
    float inv = 1.f / (e0 + e1 + e2);
    float o = (e0 * lv0 + e1 * lv1 + e2 * lv2) * inv;
    out[(size_t)n * 32 + i] = fmaxf(o, 0.f);
}

// ---------------- host ----------------

static void launch_layer(const float* feat, const float* nf, const float* efeat,
                         const int* src, const int* dst, const int* eid,
                         const float* Wr, const float* attw, const float* lw,
                         const float* hb, const float* aW, const float* ab,
                         const float* aa, float* wsf, int* wsi, float* out,
                         hipStream_t stream) {
    k_prevec<<<1, 384, 0, stream>>>(Wr, attw, wsf + O_VV);
    k_nodeproj<<<391, 128, 0, stream>>>(feat, nf, attw, wsf + O_VV, wsi + O_DEGOUT,
                                        wsf + O_FEATN, wsf + O_NFT,
                                        wsf + O_ZF, wsf + O_ZNRD);
    k_ez<<<3125, 256, 0, stream>>>(src, dst, eid, efeat, wsf + O_ZF, wsf + O_ZNRD,
                                   wsf + O_VV, wsf + O_EZ);
    k_agg<<<6250, 512, 0, stream>>>(wsi + O_ROWPTR, (const int2*)(wsi + O_EINFO),
                                    wsf + O_EZ, efeat, wsf + O_FEATN,
                                    wsf + O_YACC, wsf + O_WDENT);
    k_postAB<<<6250, 256, 0, stream>>>(wsi + O_ROWPTR, wsf + O_YACC, wsf + O_WDENT,
                                       nf, Wr, lw, hb, aW, ab, aa, out);
}

extern "C" void kernel_launch(void* const* d_in, const int* in_sizes, int n_in,
                              void* d_out, int out_size, void* d_ws, size_t ws_size,
                              hipStream_t stream) {
    const float* x     = (const float*)d_in[0];
    const float* nfeat = (const float*)d_in[1];
    const float* efeat = (const float*)d_in[2];
    const int*   src   = (const int*)d_in[3];
    const int*   dst   = (const int*)d_in[4];
    const int*   eid   = (const int*)d_in[5];
    const float* Wr1   = (const float*)d_in[6];
    const float* attw1 = (const float*)d_in[7];
    const float* lw1   = (const float*)d_in[8];
    const float* hb1   = (const float*)d_in[9];
    const float* aW1   = (const float*)d_in[10];
    const float* ab1   = (const float*)d_in[11];
    const float* aa1   = (const float*)d_in[12];
    const float* Wr2   = (const float*)d_in[13];
    const float* attw2 = (const float*)d_in[14];
    const float* lw2   = (const float*)d_in[15];
    const float* hb2   = (const float*)d_in[16];
    const float* aW2   = (const float*)d_in[17];
    const float* ab2   = (const float*)d_in[18];
    const float* aa2   = (const float*)d_in[19];

    float* wsf = (float*)d_ws;
    int*   wsi = (int*)d_ws;
    float* out = (float*)d_out;

    // zero degree counters (degin + degout)
    hipMemsetAsync(d_ws, 0, (size_t)O_ROWPTR * 4, stream);

    k_deg<<<NE / 256, 256, 0, stream>>>(src, dst, wsi + O_DEGIN, wsi + O_DEGOUT);
    k_scan<<<1, 1024, 0, stream>>>(wsi + O_DEGIN, wsi + O_ROWPTR, wsi + O_CURSOR);
    k_scatter<<<NE / 256, 256, 0, stream>>>(src, dst, eid, wsi + O_CURSOR,
                                            (int2*)(wsi + O_EINFO));

    // layer 1: feat = x -> h1 (ws)
    launch_layer(x, nfeat, efeat, src, dst, eid, Wr1, attw1, lw1, hb1, aW1, ab1, aa1,
                 wsf, wsi, wsf + O_H1, stream);
    // layer 2: feat = h1 -> d_out
    launch_layer(wsf + O_H1, nfeat, efeat, src, dst, eid, Wr2, attw2, lw2, hb2,
                 aW2, ab2, aa2, wsf, wsi, out, stream);
}